// Round 3
// 562.805 us; speedup vs baseline: 1.1576x; 1.1576x over previous
//
#include <hip/hip_runtime.h>
#include <hip/hip_bf16.h>
#include <stdint.h>

// compose_lora (fp32 in / fp32 out):
//   out = x@W^T + bias + sum_n (SCALE*w_n) * (x@A_n^T)@B_n^T
// Factored: W_eff = W + sum_n c_n * B_n@A_n  (K=128 MFMA GEMM, bf16),
// then out = x_bf16 @ W_eff^T + bias  (M=8192,N=4096,K=4096).
// R4: 651.5us. Main GEMM 394us (698 TF) = m97-structure ceiling
//     (MfmaUtil 30%, LDS_BANK_CONFLICT 3.35e7, barrier-drain bound).
// R5: main GEMM rewritten as the 256^2 8-phase template (T1+T2+T3+T4+T5):
//     512 thr / 8 waves, BK=64, LDS 128KB double-buffered, st_16x32 XOR
//     swizzle (inverse-swizzled global src + swizzled ds_read; gload_lds
//     dest linear), counted vmcnt(4) guards (never 0), raw s_barrier +
//     sched_barrier fences, setprio(1) around MFMA clusters.
//     Half-interleaved wave decomposition so each phase = one C-quadrant
//     touching exactly one A-half + one B-half (makes counted vmcnt legal).
// R6: identical resubmit — R5 bench never ran (GPUAcquisitionTimeout).
// R7: identical resubmit — R6 bench never ran (container failed twice).
//     Kernel audited for hang/fault paths: none (uniform barriers, bounded
//     addresses, 1 block/CU legal occupancy).

typedef __attribute__((ext_vector_type(4))) float f32x4;
typedef __attribute__((ext_vector_type(8))) __bf16 bf16x8;
typedef __attribute__((ext_vector_type(8))) unsigned short u16x8;

#define GLOBAL_AS(p) ((const __attribute__((address_space(1))) void*)(p))
#define LDS_AS(p)    ((__attribute__((address_space(3))) void*)(p))

__device__ __forceinline__ ushort f2b(float f) {
    __hip_bfloat16 h = __float2bfloat16(f);
    ushort u;
    __builtin_memcpy(&u, &h, 2);
    return u;
}

// ---------------------------------------------------------------------------
// prep_a: AcatT[d][k] = bf16(lA[k][d])  — coalesced via LDS tile transpose.
// lA: [128][4096] fp32. Grid: 64 blocks, each handles 64 d-columns.
// ---------------------------------------------------------------------------
__global__ __launch_bounds__(256) void prep_a_kernel(const float* __restrict__ lA,
                                                     ushort* __restrict__ AcatT) {
    __shared__ ushort tile[64][136];
    const int tid = threadIdx.x;
    const int d0 = blockIdx.x * 64;
#pragma unroll
    for (int it = 0; it < 32; ++it) {
        int k = it * 4 + (tid >> 6);
        int dc = tid & 63;
        tile[dc][k] = f2b(lA[(size_t)k * 4096 + d0 + dc]);
    }
    __syncthreads();
#pragma unroll
    for (int it = 0; it < 4; ++it) {
        int g = it * 256 + tid;
        int dc = g >> 4, slot = g & 15;
        u16x8 v;
#pragma unroll
        for (int e = 0; e < 8; ++e) v[e] = tile[dc][slot * 8 + e];
        *reinterpret_cast<u16x8*>(&AcatT[((size_t)(d0 + dc)) * 128 + slot * 8]) = v;
    }
}

// ---------------------------------------------------------------------------
// prep_b: Bcat[o][k] = bf16( (2*lw[k/16]) * lora_B[k/16][o][k%16] )
// ---------------------------------------------------------------------------
__global__ void prep_b_kernel(const float* __restrict__ lB,  // [8][4096][16]
                              const float* __restrict__ lw,  // [8]
                              ushort* __restrict__ Bcat)     // [4096][128]
{
    int idx = blockIdx.x * 256 + threadIdx.x;
    int o = idx >> 7, k = idx & 127;
    int n = k >> 4, r = k & 15;
    Bcat[idx] = f2b(2.0f * lw[n] * lB[((size_t)n * 4096 + o) * 16 + r]);
}

// ---------------------------------------------------------------------------
// cvtx: x fp32 -> bf16 workspace copy
// ---------------------------------------------------------------------------
__global__ void cvtx_kernel(const float* __restrict__ x, ushort* __restrict__ xb) {
    size_t i = ((size_t)blockIdx.x * 256 + threadIdx.x) * 8;
    const float4* xf = (const float4*)(x + i);
    float4 a = xf[0], b = xf[1];
    u16x8 r;
    r[0] = f2b(a.x); r[1] = f2b(a.y); r[2] = f2b(a.z); r[3] = f2b(a.w);
    r[4] = f2b(b.x); r[5] = f2b(b.y); r[6] = f2b(b.z); r[7] = f2b(b.w);
    *reinterpret_cast<u16x8*>(xb + i) = r;
}

// ---------------------------------------------------------------------------
// bf16 GEMM (legacy 128^2 structure): kept for the Weff build (K=128) and
// tier-2 fallback. Out[M][N] = A[M][K]*B[N][K]^T (+bias[n] / +C[m][n]).
// ---------------------------------------------------------------------------
template <bool OUT_F32, bool ADD_BIAS, bool ADD_C>
__global__ __launch_bounds__(256) void gemm_bt(
    const ushort* __restrict__ Amat, const ushort* __restrict__ Bmat,
    const float* __restrict__ aux, void* __restrict__ OutP,
    int M, int N, int K)
{
    constexpr int BK = 32;
    __shared__ __align__(16) ushort As[2 * 128 * BK];
    __shared__ __align__(16) ushort Bs[2 * 128 * BK];

    const int tid  = threadIdx.x;
    const int lane = tid & 63;
    const int w    = tid >> 6;
    const int wm   = (w >> 1) * 64;
    const int wn   = (w & 1) * 64;
    const int quad = lane >> 4;
    const int lrow = lane & 15;
    const int m0 = blockIdx.x * 128;
    const int n0 = blockIdx.y * 128;

    const int srow = (w * 2) * 16 + (lane >> 2);
    const int kofs = (lane & 3) * 8;
    const ushort* agp0 = Amat + (size_t)(m0 + srow) * K + kofs;
    const ushort* agp1 = agp0 + (size_t)16 * K;
    const ushort* bgp0 = Bmat + (size_t)(n0 + srow) * K + kofs;
    const ushort* bgp1 = bgp0 + (size_t)16 * K;
    ushort* lA00 = &As[(w * 2) * 512];
    ushort* lA01 = &As[(w * 2 + 1) * 512];
    ushort* lB00 = &Bs[(w * 2) * 512];
    ushort* lB01 = &Bs[(w * 2 + 1) * 512];

    f32x4 acc[4][4] = {};
    const int nK = K >> 6;
    for (int kt = 0; kt < nK; ++kt) {
        __syncthreads();
        __builtin_amdgcn_global_load_lds(GLOBAL_AS(agp0),      LDS_AS(lA00),        16, 0, 0);
        __builtin_amdgcn_global_load_lds(GLOBAL_AS(agp1),      LDS_AS(lA01),        16, 0, 0);
        __builtin_amdgcn_global_load_lds(GLOBAL_AS(agp0 + 32), LDS_AS(lA00 + 4096), 16, 0, 0);
        __builtin_amdgcn_global_load_lds(GLOBAL_AS(agp1 + 32), LDS_AS(lA01 + 4096), 16, 0, 0);
        __builtin_amdgcn_global_load_lds(GLOBAL_AS(bgp0),      LDS_AS(lB00),        16, 0, 0);
        __builtin_amdgcn_global_load_lds(GLOBAL_AS(bgp1),      LDS_AS(lB01),        16, 0, 0);
        __builtin_amdgcn_global_load_lds(GLOBAL_AS(bgp0 + 32), LDS_AS(lB00 + 4096), 16, 0, 0);
        __builtin_amdgcn_global_load_lds(GLOBAL_AS(bgp1 + 32), LDS_AS(lB01 + 4096), 16, 0, 0);
        agp0 += 64; agp1 += 64; bgp0 += 64; bgp1 += 64;
        __syncthreads();

#pragma unroll
        for (int h = 0; h < 2; ++h) {
            const ushort* ab = &As[h * 4096];
            const ushort* bb = &Bs[h * 4096];
            bf16x8 af[4], bfr[4];
#pragma unroll
            for (int i = 0; i < 4; ++i)
                af[i] = *reinterpret_cast<const bf16x8*>(&ab[(wm + i * 16 + lrow) * BK + quad * 8]);
#pragma unroll
            for (int j = 0; j < 4; ++j)
                bfr[j] = *reinterpret_cast<const bf16x8*>(&bb[(wn + j * 16 + lrow) * BK + quad * 8]);
#pragma unroll
            for (int i = 0; i < 4; ++i)
#pragma unroll
                for (int j = 0; j < 4; ++j)
                    acc[i][j] = __builtin_amdgcn_mfma_f32_16x16x32_bf16(af[i], bfr[j], acc[i][j], 0, 0, 0);
        }
    }

#pragma unroll
    for (int i = 0; i < 4; ++i) {
        const int row = m0 + wm + i * 16 + quad * 4;
#pragma unroll
        for (int j = 0; j < 4; ++j) {
            const int col = n0 + wn + j * 16 + lrow;
            float badd = ADD_BIAS ? aux[col] : 0.0f;
#pragma unroll
            for (int v = 0; v < 4; ++v) {
                float val = acc[i][j][v] + badd;
                if (ADD_C) val += aux[(size_t)(row + v) * N + col];
                if (OUT_F32)
                    ((float*)OutP)[(size_t)(row + v) * N + col] = val;
                else
                    ((ushort*)OutP)[(size_t)(row + v) * N + col] = f2b(val);
            }
        }
    }
}

// ---------------------------------------------------------------------------
// gemm256_bias: 256x256-tile 8-wave 8-phase bf16 GEMM (main GEMM only).
//   Out[M][N] = A[M][K] * B[N][K]^T + bias[N], fp32 out.
// Requires: M%256==0, N%256==0, K%128==0, grid = (M/256)*(N/256), 512 thr.
//
// LDS: As/Bs[buf][half][128*64] ushort, st_16x32 swizzle
//   phys_ushort(r, c) = r*64 + (c ^ (((r>>2)&1)<<4))  within each half.
// Staging: global_load_lds writes LINEAR (base + lane*16B); the global
//   source per lane is inverse-swizzled:
//     row = (w*2+c)*8 + (l>>3),  col = ((l&7)*8) ^ (((l>>5)&1)<<4)
// Wave decomposition (half-interleaved so quadrant <-> half):
//   wr=w>>2, wc=w&3; row(i)=(i>>2)*128 + wr*64 + (i&3)*16 + lrow (i=0..7)
//   col(j)=(j>>1)*128 + wc*32 + (j&1)*16 + lrow (j=0..3)
// Phase schedule per tile t (quadrants (qm,qn)), stages -> buf nxt:
//   ph1 (0,0): stage A0(t+1); vmcnt(4)   [lands B1(t)]
//   ph2 (0,1): stage B0(t+1); vmcnt(4)   [lands A1(t)]
//   ph3 (1,1): stage B1(t+1); no guard
//   ph4 (1,0): stage A1(t+1); vmcnt(4)   [lands A0,B0(t+1)]
// Every staged region has vmcnt(4)+barrier strictly before its first read.
// ---------------------------------------------------------------------------
__global__ __launch_bounds__(512, 2) void gemm256_bias(
    const ushort* __restrict__ Amat, const ushort* __restrict__ Bmat,
    const float* __restrict__ bias, float* __restrict__ Out,
    int M, int N, int K)
{
    __shared__ __align__(16) ushort As[2][2][128 * 64];
    __shared__ __align__(16) ushort Bs[2][2][128 * 64];

    const int tid  = threadIdx.x;
    const int l    = tid & 63;
    const int w    = tid >> 6;          // 0..7
    const int wr   = w >> 2;            // 0..1
    const int wc   = w & 3;             // 0..3
    const int quad = l >> 4;
    const int lrow = l & 15;

    // XCD-aware bijective block swizzle (gridDim.x % 8 == 0 by construction)
    const int nbn = N >> 8;
    const int cpx = gridDim.x >> 3;
    int id = ((int)blockIdx.x & 7) * cpx + ((int)blockIdx.x >> 3);
    const int m0 = (id / nbn) * 256;
    const int n0 = (id % nbn) * 256;

    // ---- staging addresses (inverse-swizzled global source, linear LDS dest)
    const int cOff = ((l & 7) * 8) ^ (((l >> 5) & 1) << 4);
    const ushort* aBase = Amat + (size_t)(m0 + (w * 2) * 8 + (l >> 3)) * K + cOff;
    const ushort* bBase = Bmat + (size_t)(n0 + (w * 2) * 8 + (l >> 3)) * K + cOff;
    const int dC = 8 * K;               // c=1: +8 rows
    const int dH = 128 * K;             // half 1: +128 rows
    const int st0 = w * 1024;           // ushort offset of this wave's call-0 chunk
    const int st1 = w * 1024 + 512;

    // ---- ds_read fragment addressing (swizzled)
    const int aRow0 = wr * 64 + lrow;           // + i*16
    const int bCol0 = wc * 32 + lrow;           // + j*16
    const int kqf = ((lrow >> 2) & 1) << 4;     // st_16x32 flip (ushort units)
    const int kq0 = (quad * 8) ^ kqf;           // k-half 0
    const int kq1 = (32 + quad * 8) ^ kqf;      // k-half 1

    f32x4 acc[8][4] = {};
    bf16x8 af[4][2], bf[2][2];

    const int nT = K >> 6;              // K/64, must be even

#define GLDS(gp, lp) __builtin_amdgcn_global_load_lds(GLOBAL_AS(gp), LDS_AS(lp), 16, 0, 0)

#define LOAD_AF(cur_, half_) do { \
    af[0][0] = *reinterpret_cast<const bf16x8*>(&As[cur_][half_][(aRow0 +  0) * 64 + kq0]); \
    af[0][1] = *reinterpret_cast<const bf16x8*>(&As[cur_][half_][(aRow0 +  0) * 64 + kq1]); \
    af[1][0] = *reinterpret_cast<const bf16x8*>(&As[cur_][half_][(aRow0 + 16) * 64 + kq0]); \
    af[1][1] = *reinterpret_cast<const bf16x8*>(&As[cur_][half_][(aRow0 + 16) * 64 + kq1]); \
    af[2][0] = *reinterpret_cast<const bf16x8*>(&As[cur_][half_][(aRow0 + 32) * 64 + kq0]); \
    af[2][1] = *reinterpret_cast<const bf16x8*>(&As[cur_][half_][(aRow0 + 32) * 64 + kq1]); \
    af[3][0] = *reinterpret_cast<const bf16x8*>(&As[cur_][half_][(aRow0 + 48) * 64 + kq0]); \
    af[3][1] = *reinterpret_cast<const bf16x8*>(&As[cur_][half_][(aRow0 + 48) * 64 + kq1]); \
} while (0)

#define LOAD_BF(cur_, half_) do { \
    bf[0][0] = *reinterpret_cast<const bf16x8*>(&Bs[cur_][half_][(bCol0 +  0) * 64 + kq0]); \
    bf[0][1] = *reinterpret_cast<const bf16x8*>(&Bs[cur_][half_][(bCol0 +  0) * 64 + kq1]); \
    bf[1][0] = *reinterpret_cast<const bf16x8*>(&Bs[cur_][half_][(bCol0 + 16) * 64 + kq0]); \
    bf[1][1] = *reinterpret_cast<const bf16x8*>(&Bs[cur_][half_][(bCol0 + 16) * 64 + kq1]); \
} while (0)

#define MFMA1(qm_, qn_, i_, j_, kh_) \
    acc[(qm_) * 4 + (i_)][(qn_) * 2 + (j_)] = __builtin_amdgcn_mfma_f32_16x16x32_bf16( \
        af[i_][kh_], bf[j_][kh_], acc[(qm_) * 4 + (i_)][(qn_) * 2 + (j_)], 0, 0, 0)

#define MFMA_QUAD(qm_, qn_) do { \
    MFMA1(qm_,qn_,0,0,0); MFMA1(qm_,qn_,0,1,0); MFMA1(qm_,qn_,1,0,0); MFMA1(qm_,qn_,1,1,0); \
    MFMA1(qm_,qn_,2,0,0); MFMA1(qm_,qn_,2,1,0); MFMA1(qm_,qn_,3,0,0); MFMA1(qm_,qn_,3,1,0); \
    MFMA1(qm_,qn_,0,0,1); MFMA1(qm_,qn_,0,1,1); MFMA1(qm_,qn_,1,0,1); MFMA1(qm_,qn_,1,1,1); \
    MFMA1(qm_,qn_,2,0,1); MFMA1(qm_,qn_,2,1,1); MFMA1(qm_,qn_,3,0,1); MFMA1(qm_,qn_,3,1,1); \
} while (0)

#define BAR_MID() do { \
    asm volatile("" ::: "memory"); \
    __builtin_amdgcn_s_barrier(); \
    __builtin_amdgcn_sched_barrier(0); \
    asm volatile("s_waitcnt lgkmcnt(0)" ::: "memory"); \
    __builtin_amdgcn_sched_barrier(0); \
    __builtin_amdgcn_s_setprio(1); \
} while (0)

#define BAR_END() do { \
    __builtin_amdgcn_s_setprio(0); \
    asm volatile("" ::: "memory"); \
    __builtin_amdgcn_s_barrier(); \
    __builtin_amdgcn_sched_barrier(0); \
} while (0)

#define VGUARD() asm volatile("s_waitcnt vmcnt(4)" ::: "memory")

#define TILE_STEP(cur_, nxt_, tt_) do { \
    const int ks = ((tt_) + 1) << 6; \
    const bool doSt = ((tt_) + 1) < nT; \
    /* phase 1: quadrant (0,0) */ \
    LOAD_AF(cur_, 0); LOAD_BF(cur_, 0); \
    if (doSt) { GLDS(aBase + ks, &As[nxt_][0][st0]); GLDS(aBase + dC + ks, &As[nxt_][0][st1]); } \
    BAR_MID(); MFMA_QUAD(0, 0); VGUARD(); BAR_END(); \
    /* phase 2: quadrant (0,1) */ \
    LOAD_BF(cur_, 1); \
    if (doSt) { GLDS(bBase + ks, &Bs[nxt_][0][st0]); GLDS(bBase + dC + ks, &Bs[nxt_][0][st1]); } \
    BAR_MID(); MFMA_QUAD(0, 1); VGUARD(); BAR_END(); \
    /* phase 3: quadrant (1,1) */ \
    LOAD_AF(cur_, 1); \
    if (doSt) { GLDS(bBase + dH + ks, &Bs[nxt_][1][st0]); GLDS(bBase + dH + dC + ks, &Bs[nxt_][1][st1]); } \
    BAR_MID(); MFMA_QUAD(1, 1); BAR_END(); \
    /* phase 4: quadrant (1,0) */ \
    LOAD_BF(cur_, 0); \
    if (doSt) { GLDS(aBase + dH + ks, &As[nxt_][1][st0]); GLDS(aBase + dH + dC + ks, &As[nxt_][1][st1]); } \
    BAR_MID(); MFMA_QUAD(1, 0); VGUARD(); BAR_END(); \
} while (0)

    // ---- prologue: stage tile 0 into buf 0; order A0,B0 (oldest), B1, A1
    GLDS(aBase,           &As[0][0][st0]); GLDS(aBase + dC,      &As[0][0][st1]);
    GLDS(bBase,           &Bs[0][0][st0]); GLDS(bBase + dC,      &Bs[0][0][st1]);
    GLDS(bBase + dH,      &Bs[0][1][st0]); GLDS(bBase + dH + dC, &Bs[0][1][st1]);
    GLDS(aBase + dH,      &As[0][1][st0]); GLDS(aBase + dH + dC, &As[0][1][st1]);
    asm volatile("s_waitcnt vmcnt(4)" ::: "memory");   // A0,B0 landed; B1,A1 in flight
    asm volatile("" ::: "memory");
    __builtin_amdgcn_s_barrier();
    __builtin_amdgcn_sched_barrier(0);

#pragma unroll 1
    for (int t = 0; t < nT; t += 2) {
        TILE_STEP(0, 1, t);
        TILE_STEP(1, 0, t + 1);
    }

    // ---- epilogue: C/D layout col=lrow, row=quad*4+v [m89-verified]
#pragma unroll
    for (int i = 0; i < 8; ++i) {
        const int row = m0 + (i >> 2) * 128 + wr * 64 + (i & 3) * 16 + quad * 4;
#pragma unroll
        for (int j = 0; j < 4; ++j) {
            const int col = n0 + (j >> 1) * 128 + wc * 32 + (j & 1) * 16 + lrow;
            const float badd = bias[col];
#pragma unroll
            for (int v = 0; v < 4; ++v)
                Out[(size_t)(row + v) * N + col] = acc[i][j][v] + badd;
        }
    }

#undef GLDS
#undef LOAD_AF
#undef LOAD_BF
#undef MFMA1
#undef MFMA_QUAD
#undef BAR_MID
#undef BAR_END
#undef VGUARD
#undef TILE_STEP
}

// ---------------------------------------------------------------------------
// tier-2 main GEMM (ws too small for xb): A fp32 converted in-kernel.
// ---------------------------------------------------------------------------
__global__ __launch_bounds__(256) void gemm_af32(
    const float* __restrict__ Af, const ushort* __restrict__ Bmat,
    const float* __restrict__ bias, float* __restrict__ Out,
    int M, int N, int K)
{
    constexpr int BM = 128, BN = 128, BK = 32;
    __shared__ __align__(16) ushort As[BM * BK];
    __shared__ __align__(16) ushort Bs[BN * BK];

    const int tid  = threadIdx.x;
    const int lane = tid & 63;
    const int w    = tid >> 6;
    const int wm   = (w >> 1) * 64;
    const int wn   = (w & 1) * 64;
    const int quad = lane >> 4;
    const int lrow = lane & 15;
    const int m0 = blockIdx.x * BM;
    const int n0 = blockIdx.y * BN;

    const int srow = (w * 2) * 16 + (lane >> 2);
    const int kofs = (lane & 3) * 8;
    const ushort* bgp0 = Bmat + (size_t)(n0 + srow) * K + kofs;
    const ushort* bgp1 = bgp0 + (size_t)16 * K;
    ushort* lB0 = &Bs[(w * 2) * 512];
    ushort* lB1 = &Bs[(w * 2 + 1) * 512];

    f32x4 acc[4][4] = {};
    const int nK = K / BK;
    for (int kt = 0; kt < nK; ++kt) {
        __syncthreads();
        __builtin_amdgcn_global_load_lds(GLOBAL_AS(bgp0), LDS_AS(lB0), 16, 0, 0);
        __builtin_amdgcn_global_load_lds(GLOBAL_AS(bgp1), LDS_AS(lB1), 16, 0, 0);
        bgp0 += BK; bgp1 += BK;
#pragma unroll
        for (int gg = 0; gg < 2; ++gg) {
            int g = tid + gg * 256;
            int row = g >> 2, kc = (g & 3) * 8;
            const float* src = Af + (size_t)(m0 + row) * K + (size_t)kt * BK + kc;
            float4 a = *(const float4*)src;
            float4 b = *(const float4*)(src + 4);
            u16x8 r;
            r[0] = f2b(a.x); r[1] = f2b(a.y); r[2] = f2b(a.z); r[3] = f2b(a.w);
            r[4] = f2b(b.x); r[5] = f2b(b.y); r[6] = f2b(b.z); r[7] = f2b(b.w);
            *reinterpret_cast<u16x8*>(&As[row * BK + kc]) = r;
        }
        __syncthreads();

        bf16x8 af[4], bfr[4];
#pragma unroll
        for (int i = 0; i < 4; ++i)
            af[i] = *reinterpret_cast<const bf16x8*>(&As[(wm + i * 16 + lrow) * BK + quad * 8]);
#pragma unroll
        for (int j = 0; j < 4; ++j)
            bfr[j] = *reinterpret_cast<const bf16x8*>(&Bs[(wn + j * 16 + lrow) * BK + quad * 8]);
#pragma unroll
        for (int i = 0; i < 4; ++i)
#pragma unroll
            for (int j = 0; j < 4; ++j)
                acc[i][j] = __builtin_amdgcn_mfma_f32_16x16x32_bf16(af[i], bfr[j], acc[i][j], 0, 0, 0);
    }

#pragma unroll
    for (int i = 0; i < 4; ++i) {
        const int row = m0 + wm + i * 16 + quad * 4;
#pragma unroll
        for (int j = 0; j < 4; ++j) {
            const int col = n0 + wn + j * 16 + lrow;
            float badd = bias[col];
#pragma unroll
            for (int v = 0; v < 4; ++v)
                Out[(size_t)(row + v) * N + col] = acc[i][j][v] + badd;
        }
    }
}

// ---------------------------------------------------------------------------
// emergency fallback (tiny ws): pure fp32, slow but correct
// ---------------------------------------------------------------------------
__global__ void naive_kernel(const float* __restrict__ x, const float* __restrict__ lA,
                             const float* __restrict__ lB, const float* __restrict__ W,
                             const float* __restrict__ bias, const float* __restrict__ lw,
                             float* __restrict__ out)
{
    __shared__ float xs[4096];
    __shared__ float h[128];
    const int m = blockIdx.x;
    for (int d = threadIdx.x; d < 4096; d += 256)
        xs[d] = x[(size_t)m * 4096 + d];
    __syncthreads();
    for (int k = threadIdx.x; k < 128; k += 256) {
        const float* arow = lA + (size_t)k * 4096;
        float s = 0.f;
        for (int d = 0; d < 4096; ++d) s += xs[d] * arow[d];
        h[k] = s;
    }
    __syncthreads();
    for (int o = threadIdx.x; o < 4096; o += 256) {
        const float* wrow = W + (size_t)o * 4096;
        float s = bias[o];
        for (int d = 0; d < 4096; ++d) s += xs[d] * wrow[d];
        for (int n = 0; n < 8; ++n) {
            const float* brow = lB + ((size_t)n * 4096 + o) * 16;
            float t = 0.f;
            for (int r = 0; r < 16; ++r) t += h[n * 16 + r] * brow[r];
            s += 2.0f * lw[n] * t;
        }
        out[(size_t)m * 4096 + o] = s;
    }
}

// ---------------------------------------------------------------------------
extern "C" void kernel_launch(void* const* d_in, const int* in_sizes, int n_in,
                              void* d_out, int out_size, void* d_ws, size_t ws_size,
                              hipStream_t stream)
{
    const float* x    = (const float*)d_in[0];  // [4,2048,4096]
    const float* lA   = (const float*)d_in[1];  // [8,16,4096]
    const float* lB   = (const float*)d_in[2];  // [8,4096,16]
    const float* W    = (const float*)d_in[3];  // [4096,4096]
    const float* bias = (const float*)d_in[4];  // [4096]
    const float* lw   = (const float*)d_in[5];  // [8]
    float* out = (float*)d_out;                 // [8192,4096] fp32

    // ws layout (bf16): [Bcat 1MiB][AcatT 1MiB][Weff 32MiB][xb 64MiB]
    ushort* Bcat  = (ushort*)d_ws;
    ushort* AcatT = Bcat + (size_t)4096 * 128;
    ushort* Weff  = AcatT + (size_t)4096 * 128;
    ushort* xb    = Weff + (size_t)4096 * 4096;
    const size_t need_t2 = (2 * (size_t)4096 * 128 + (size_t)4096 * 4096) * 2;
    const size_t need_t1 = need_t2 + (size_t)8192 * 4096 * 2;

    if (ws_size >= need_t2) {
        prep_a_kernel<<<64, 256, 0, stream>>>(lA, AcatT);
        prep_b_kernel<<<2048, 256, 0, stream>>>(lB, lw, Bcat);
        // Weff[o][d] = W[o][d] + Bcat[o][:]·AcatT[d][:]   (bf16 out, K=128)
        gemm_bt<false, false, true><<<dim3(32, 32), 256, 0, stream>>>(
            Bcat, AcatT, W, Weff, 4096, 4096, 128);
        if (ws_size >= need_t1) {
            cvtx_kernel<<<16384, 256, 0, stream>>>(x, xb);
            // out[m][o] = xb[m][:]·Weff[o][:] + bias[o]   (fp32 out)
            // 256^2 8-phase kernel: grid = (8192/256)*(4096/256) = 512
            gemm256_bias<<<dim3(512), 512, 0, stream>>>(
                xb, Weff, bias, out, 8192, 4096, 4096);
        } else {
            gemm_af32<<<dim3(64, 32), 256, 0, stream>>>(
                x, Weff, bias, out, 8192, 4096, 4096);
        }
    } else {
        naive_kernel<<<8192, 256, 0, stream>>>(x, lA, lB, W, bias, lw, out);
    }
}

// Round 4
// 546.586 us; speedup vs baseline: 1.1919x; 1.0297x over previous
//
#include <hip/hip_runtime.h>
#include <hip/hip_bf16.h>
#include <stdint.h>

// compose_lora (fp32 in / fp32 out):
//   out = x@W^T + bias + sum_n (SCALE*w_n) * (x@A_n^T)@B_n^T
// Factored: W_eff = W + sum_n c_n * B_n@A_n  (K=128 MFMA GEMM, bf16),
// then out = x_bf16 @ W_eff^T + bias  (M=8192,N=4096,K=4096).
// R4: 651.5us. Main GEMM 394us (698 TF) = m97-structure ceiling.
// R5(ran as R7): 562.8us. gemm256 8-phase = 307us (897 TF), MfmaUtil 37.9,
//     BANK_CONFLICT 2.94e7 — swizzle WRONG: 1-bit flip ((r>>2)&1)<<4 leaves
//     16B-slots 4-7 unused (16 lanes/slot = 2x baseline conflict).
// R8: 3-bit swizzle fix (guide G4): phys col = logical col ^ ((row&7)<<3)
//     (ushort units). Slot = quad ^ (lrow&7) -> all 8 slots, 8 lanes/slot
//     = conflict-free baseline. Staging source inverse-permuted to match
//     (rule #21: both-sides-or-neither; gload_lds dest stays linear).
//     Predict: conflicts <1e6, MfmaUtil ~55, gemm256 ~230us, total ~485us.

typedef __attribute__((ext_vector_type(4))) float f32x4;
typedef __attribute__((ext_vector_type(8))) __bf16 bf16x8;
typedef __attribute__((ext_vector_type(8))) unsigned short u16x8;

#define GLOBAL_AS(p) ((const __attribute__((address_space(1))) void*)(p))
#define LDS_AS(p)    ((__attribute__((address_space(3))) void*)(p))

__device__ __forceinline__ ushort f2b(float f) {
    __hip_bfloat16 h = __float2bfloat16(f);
    ushort u;
    __builtin_memcpy(&u, &h, 2);
    return u;
}

// ---------------------------------------------------------------------------
// prep_a: AcatT[d][k] = bf16(lA[k][d])  — coalesced via LDS tile transpose.
// lA: [128][4096] fp32. Grid: 64 blocks, each handles 64 d-columns.
// ---------------------------------------------------------------------------
__global__ __launch_bounds__(256) void prep_a_kernel(const float* __restrict__ lA,
                                                     ushort* __restrict__ AcatT) {
    __shared__ ushort tile[64][136];
    const int tid = threadIdx.x;
    const int d0 = blockIdx.x * 64;
#pragma unroll
    for (int it = 0; it < 32; ++it) {
        int k = it * 4 + (tid >> 6);
        int dc = tid & 63;
        tile[dc][k] = f2b(lA[(size_t)k * 4096 + d0 + dc]);
    }
    __syncthreads();
#pragma unroll
    for (int it = 0; it < 4; ++it) {
        int g = it * 256 + tid;
        int dc = g >> 4, slot = g & 15;
        u16x8 v;
#pragma unroll
        for (int e = 0; e < 8; ++e) v[e] = tile[dc][slot * 8 + e];
        *reinterpret_cast<u16x8*>(&AcatT[((size_t)(d0 + dc)) * 128 + slot * 8]) = v;
    }
}

// ---------------------------------------------------------------------------
// prep_b: Bcat[o][k] = bf16( (2*lw[k/16]) * lora_B[k/16][o][k%16] )
// ---------------------------------------------------------------------------
__global__ void prep_b_kernel(const float* __restrict__ lB,  // [8][4096][16]
                              const float* __restrict__ lw,  // [8]
                              ushort* __restrict__ Bcat)     // [4096][128]
{
    int idx = blockIdx.x * 256 + threadIdx.x;
    int o = idx >> 7, k = idx & 127;
    int n = k >> 4, r = k & 15;
    Bcat[idx] = f2b(2.0f * lw[n] * lB[((size_t)n * 4096 + o) * 16 + r]);
}

// ---------------------------------------------------------------------------
// cvtx: x fp32 -> bf16 workspace copy
// ---------------------------------------------------------------------------
__global__ void cvtx_kernel(const float* __restrict__ x, ushort* __restrict__ xb) {
    size_t i = ((size_t)blockIdx.x * 256 + threadIdx.x) * 8;
    const float4* xf = (const float4*)(x + i);
    float4 a = xf[0], b = xf[1];
    u16x8 r;
    r[0] = f2b(a.x); r[1] = f2b(a.y); r[2] = f2b(a.z); r[3] = f2b(a.w);
    r[4] = f2b(b.x); r[5] = f2b(b.y); r[6] = f2b(b.z); r[7] = f2b(b.w);
    *reinterpret_cast<u16x8*>(xb + i) = r;
}

// ---------------------------------------------------------------------------
// bf16 GEMM (legacy 128^2 structure): kept for the Weff build (K=128) and
// tier-2 fallback. Out[M][N] = A[M][K]*B[N][K]^T (+bias[n] / +C[m][n]).
// ---------------------------------------------------------------------------
template <bool OUT_F32, bool ADD_BIAS, bool ADD_C>
__global__ __launch_bounds__(256) void gemm_bt(
    const ushort* __restrict__ Amat, const ushort* __restrict__ Bmat,
    const float* __restrict__ aux, void* __restrict__ OutP,
    int M, int N, int K)
{
    constexpr int BK = 32;
    __shared__ __align__(16) ushort As[2 * 128 * BK];
    __shared__ __align__(16) ushort Bs[2 * 128 * BK];

    const int tid  = threadIdx.x;
    const int lane = tid & 63;
    const int w    = tid >> 6;
    const int wm   = (w >> 1) * 64;
    const int wn   = (w & 1) * 64;
    const int quad = lane >> 4;
    const int lrow = lane & 15;
    const int m0 = blockIdx.x * 128;
    const int n0 = blockIdx.y * 128;

    const int srow = (w * 2) * 16 + (lane >> 2);
    const int kofs = (lane & 3) * 8;
    const ushort* agp0 = Amat + (size_t)(m0 + srow) * K + kofs;
    const ushort* agp1 = agp0 + (size_t)16 * K;
    const ushort* bgp0 = Bmat + (size_t)(n0 + srow) * K + kofs;
    const ushort* bgp1 = bgp0 + (size_t)16 * K;
    ushort* lA00 = &As[(w * 2) * 512];
    ushort* lA01 = &As[(w * 2 + 1) * 512];
    ushort* lB00 = &Bs[(w * 2) * 512];
    ushort* lB01 = &Bs[(w * 2 + 1) * 512];

    f32x4 acc[4][4] = {};
    const int nK = K >> 6;
    for (int kt = 0; kt < nK; ++kt) {
        __syncthreads();
        __builtin_amdgcn_global_load_lds(GLOBAL_AS(agp0),      LDS_AS(lA00),        16, 0, 0);
        __builtin_amdgcn_global_load_lds(GLOBAL_AS(agp1),      LDS_AS(lA01),        16, 0, 0);
        __builtin_amdgcn_global_load_lds(GLOBAL_AS(agp0 + 32), LDS_AS(lA00 + 4096), 16, 0, 0);
        __builtin_amdgcn_global_load_lds(GLOBAL_AS(agp1 + 32), LDS_AS(lA01 + 4096), 16, 0, 0);
        __builtin_amdgcn_global_load_lds(GLOBAL_AS(bgp0),      LDS_AS(lB00),        16, 0, 0);
        __builtin_amdgcn_global_load_lds(GLOBAL_AS(bgp1),      LDS_AS(lB01),        16, 0, 0);
        __builtin_amdgcn_global_load_lds(GLOBAL_AS(bgp0 + 32), LDS_AS(lB00 + 4096), 16, 0, 0);
        __builtin_amdgcn_global_load_lds(GLOBAL_AS(bgp1 + 32), LDS_AS(lB01 + 4096), 16, 0, 0);
        agp0 += 64; agp1 += 64; bgp0 += 64; bgp1 += 64;
        __syncthreads();

#pragma unroll
        for (int h = 0; h < 2; ++h) {
            const ushort* ab = &As[h * 4096];
            const ushort* bb = &Bs[h * 4096];
            bf16x8 af[4], bfr[4];
#pragma unroll
            for (int i = 0; i < 4; ++i)
                af[i] = *reinterpret_cast<const bf16x8*>(&ab[(wm + i * 16 + lrow) * BK + quad * 8]);
#pragma unroll
            for (int j = 0; j < 4; ++j)
                bfr[j] = *reinterpret_cast<const bf16x8*>(&bb[(wn + j * 16 + lrow) * BK + quad * 8]);
#pragma unroll
            for (int i = 0; i < 4; ++i)
#pragma unroll
                for (int j = 0; j < 4; ++j)
                    acc[i][j] = __builtin_amdgcn_mfma_f32_16x16x32_bf16(af[i], bfr[j], acc[i][j], 0, 0, 0);
        }
    }

#pragma unroll
    for (int i = 0; i < 4; ++i) {
        const int row = m0 + wm + i * 16 + quad * 4;
#pragma unroll
        for (int j = 0; j < 4; ++j) {
            const int col = n0 + wn + j * 16 + lrow;
            float badd = ADD_BIAS ? aux[col] : 0.0f;
#pragma unroll
            for (int v = 0; v < 4; ++v) {
                float val = acc[i][j][v] + badd;
                if (ADD_C) val += aux[(size_t)(row + v) * N + col];
                if (OUT_F32)
                    ((float*)OutP)[(size_t)(row + v) * N + col] = val;
                else
                    ((ushort*)OutP)[(size_t)(row + v) * N + col] = f2b(val);
            }
        }
    }
}

// ---------------------------------------------------------------------------
// gemm256_bias: 256x256-tile 8-wave 8-phase bf16 GEMM (main GEMM only).
//   Out[M][N] = A[M][K] * B[N][K]^T + bias[N], fp32 out.
// Requires: M%256==0, N%256==0, K%128==0, grid = (M/256)*(N/256), 512 thr.
//
// LDS: As/Bs[buf][half][128*64] ushort, 3-bit XOR swizzle (R8):
//   phys_ushort(r, c) = r*64 + (c ^ ((r&7)<<3))  within each half.
//   Read slot = quad ^ (lrow&7) -> 8 lanes per 16B slot (baseline, no
//   counted conflict). Rows r, r+8 alias (2-way, free per m136).
// Staging: global_load_lds writes LINEAR (base + lane*16B); the global
//   source per lane is inverse-swizzled:
//     row = (w*2+c)*8 + (l>>3),  col = ((l&7)*8) ^ ((l>>3)<<3)
//   (chunk rows 8-aligned so row&7 == l>>3; each 8-lane group still covers
//   one full 128B row -> coalescing preserved.)
// Wave decomposition (half-interleaved so quadrant <-> half):
//   wr=w>>2, wc=w&3; row(i)=(i>>2)*128 + wr*64 + (i&3)*16 + lrow (i=0..7)
//   col(j)=(j>>1)*128 + wc*32 + (j&1)*16 + lrow (j=0..3)
// Phase schedule per tile t (quadrants (qm,qn)), stages -> buf nxt:
//   ph1 (0,0): stage A0(t+1); vmcnt(4)   [lands B1(t)]
//   ph2 (0,1): stage B0(t+1); vmcnt(4)   [lands A1(t)]
//   ph3 (1,1): stage B1(t+1); no guard
//   ph4 (1,0): stage A1(t+1); vmcnt(4)   [lands A0,B0(t+1)]
// Every staged region has vmcnt(4)+barrier strictly before its first read.
// ---------------------------------------------------------------------------
__global__ __launch_bounds__(512, 2) void gemm256_bias(
    const ushort* __restrict__ Amat, const ushort* __restrict__ Bmat,
    const float* __restrict__ bias, float* __restrict__ Out,
    int M, int N, int K)
{
    __shared__ __align__(16) ushort As[2][2][128 * 64];
    __shared__ __align__(16) ushort Bs[2][2][128 * 64];

    const int tid  = threadIdx.x;
    const int l    = tid & 63;
    const int w    = tid >> 6;          // 0..7
    const int wr   = w >> 2;            // 0..1
    const int wc   = w & 3;             // 0..3
    const int quad = l >> 4;
    const int lrow = l & 15;

    // XCD-aware bijective block swizzle (gridDim.x % 8 == 0 by construction)
    const int nbn = N >> 8;
    const int cpx = gridDim.x >> 3;
    int id = ((int)blockIdx.x & 7) * cpx + ((int)blockIdx.x >> 3);
    const int m0 = (id / nbn) * 256;
    const int n0 = (id % nbn) * 256;

    // ---- staging addresses (inverse-swizzled global source, linear LDS dest)
    const int cOff = ((l & 7) * 8) ^ ((l >> 3) << 3);
    const ushort* aBase = Amat + (size_t)(m0 + (w * 2) * 8 + (l >> 3)) * K + cOff;
    const ushort* bBase = Bmat + (size_t)(n0 + (w * 2) * 8 + (l >> 3)) * K + cOff;
    const int dC = 8 * K;               // c=1: +8 rows
    const int dH = 128 * K;             // half 1: +128 rows
    const int st0 = w * 1024;           // ushort offset of this wave's call-0 chunk
    const int st1 = w * 1024 + 512;

    // ---- ds_read fragment addressing (swizzled)
    const int aRow0 = wr * 64 + lrow;           // + i*16
    const int bCol0 = wc * 32 + lrow;           // + j*16
    const int kqf = (lrow & 7) << 3;            // 3-bit swizzle flip (ushort units)
    const int kq0 = (quad * 8) ^ kqf;           // k-half 0
    const int kq1 = (32 + quad * 8) ^ kqf;      // k-half 1

    f32x4 acc[8][4] = {};
    bf16x8 af[4][2], bf[2][2];

    const int nT = K >> 6;              // K/64, must be even

#define GLDS(gp, lp) __builtin_amdgcn_global_load_lds(GLOBAL_AS(gp), LDS_AS(lp), 16, 0, 0)

#define LOAD_AF(cur_, half_) do { \
    af[0][0] = *reinterpret_cast<const bf16x8*>(&As[cur_][half_][(aRow0 +  0) * 64 + kq0]); \
    af[0][1] = *reinterpret_cast<const bf16x8*>(&As[cur_][half_][(aRow0 +  0) * 64 + kq1]); \
    af[1][0] = *reinterpret_cast<const bf16x8*>(&As[cur_][half_][(aRow0 + 16) * 64 + kq0]); \
    af[1][1] = *reinterpret_cast<const bf16x8*>(&As[cur_][half_][(aRow0 + 16) * 64 + kq1]); \
    af[2][0] = *reinterpret_cast<const bf16x8*>(&As[cur_][half_][(aRow0 + 32) * 64 + kq0]); \
    af[2][1] = *reinterpret_cast<const bf16x8*>(&As[cur_][half_][(aRow0 + 32) * 64 + kq1]); \
    af[3][0] = *reinterpret_cast<const bf16x8*>(&As[cur_][half_][(aRow0 + 48) * 64 + kq0]); \
    af[3][1] = *reinterpret_cast<const bf16x8*>(&As[cur_][half_][(aRow0 + 48) * 64 + kq1]); \
} while (0)

#define LOAD_BF(cur_, half_) do { \
    bf[0][0] = *reinterpret_cast<const bf16x8*>(&Bs[cur_][half_][(bCol0 +  0) * 64 + kq0]); \
    bf[0][1] = *reinterpret_cast<const bf16x8*>(&Bs[cur_][half_][(bCol0 +  0) * 64 + kq1]); \
    bf[1][0] = *reinterpret_cast<const bf16x8*>(&Bs[cur_][half_][(bCol0 + 16) * 64 + kq0]); \
    bf[1][1] = *reinterpret_cast<const bf16x8*>(&Bs[cur_][half_][(bCol0 + 16) * 64 + kq1]); \
} while (0)

#define MFMA1(qm_, qn_, i_, j_, kh_) \
    acc[(qm_) * 4 + (i_)][(qn_) * 2 + (j_)] = __builtin_amdgcn_mfma_f32_16x16x32_bf16( \
        af[i_][kh_], bf[j_][kh_], acc[(qm_) * 4 + (i_)][(qn_) * 2 + (j_)], 0, 0, 0)

#define MFMA_QUAD(qm_, qn_) do { \
    MFMA1(qm_,qn_,0,0,0); MFMA1(qm_,qn_,0,1,0); MFMA1(qm_,qn_,1,0,0); MFMA1(qm_,qn_,1,1,0); \
    MFMA1(qm_,qn_,2,0,0); MFMA1(qm_,qn_,2,1,0); MFMA1(qm_,qn_,3,0,0); MFMA1(qm_,qn_,3,1,0); \
    MFMA1(qm_,qn_,0,0,1); MFMA1(qm_,qn_,0,1,1); MFMA1(qm_,qn_,1,0,1); MFMA1(qm_,qn_,1,1,1); \
    MFMA1(qm_,qn_,2,0,1); MFMA1(qm_,qn_,2,1,1); MFMA1(qm_,qn_,3,0,1); MFMA1(qm_,qn_,3,1,1); \
} while (0)

#define BAR_MID() do { \
    asm volatile("" ::: "memory"); \
    __builtin_amdgcn_s_barrier(); \
    __builtin_amdgcn_sched_barrier(0); \
    asm volatile("s_waitcnt lgkmcnt(0)" ::: "memory"); \
    __builtin_amdgcn_sched_barrier(0); \
    __builtin_amdgcn_s_setprio(1); \
} while (0)

#define BAR_END() do { \
    __builtin_amdgcn_s_setprio(0); \
    asm volatile("" ::: "memory"); \
    __builtin_amdgcn_s_barrier(); \
    __builtin_amdgcn_sched_barrier(0); \
} while (0)

#define VGUARD() asm volatile("s_waitcnt vmcnt(4)" ::: "memory")

#define TILE_STEP(cur_, nxt_, tt_) do { \
    const int ks = ((tt_) + 1) << 6; \
    const bool doSt = ((tt_) + 1) < nT; \
    /* phase 1: quadrant (0,0) */ \
    LOAD_AF(cur_, 0); LOAD_BF(cur_, 0); \
    if (doSt) { GLDS(aBase + ks, &As[nxt_][0][st0]); GLDS(aBase + dC + ks, &As[nxt_][0][st1]); } \
    BAR_MID(); MFMA_QUAD(0, 0); VGUARD(); BAR_END(); \
    /* phase 2: quadrant (0,1) */ \
    LOAD_BF(cur_, 1); \
    if (doSt) { GLDS(bBase + ks, &Bs[nxt_][0][st0]); GLDS(bBase + dC + ks, &Bs[nxt_][0][st1]); } \
    BAR_MID(); MFMA_QUAD(0, 1); VGUARD(); BAR_END(); \
    /* phase 3: quadrant (1,1) */ \
    LOAD_AF(cur_, 1); \
    if (doSt) { GLDS(bBase + dH + ks, &Bs[nxt_][1][st0]); GLDS(bBase + dH + dC + ks, &Bs[nxt_][1][st1]); } \
    BAR_MID(); MFMA_QUAD(1, 1); BAR_END(); \
    /* phase 4: quadrant (1,0) */ \
    LOAD_BF(cur_, 0); \
    if (doSt) { GLDS(aBase + dH + ks, &As[nxt_][1][st0]); GLDS(aBase + dH + dC + ks, &As[nxt_][1][st1]); } \
    BAR_MID(); MFMA_QUAD(1, 0); VGUARD(); BAR_END(); \
} while (0)

    // ---- prologue: stage tile 0 into buf 0; order A0,B0 (oldest), B1, A1
    GLDS(aBase,           &As[0][0][st0]); GLDS(aBase + dC,      &As[0][0][st1]);
    GLDS(bBase,           &Bs[0][0][st0]); GLDS(bBase + dC,      &Bs[0][0][st1]);
    GLDS(bBase + dH,      &Bs[0][1][st0]); GLDS(bBase + dH + dC, &Bs[0][1][st1]);
    GLDS(aBase + dH,      &As[0][1][st0]); GLDS(aBase + dH + dC, &As[0][1][st1]);
    asm volatile("s_waitcnt vmcnt(4)" ::: "memory");   // A0,B0 landed; B1,A1 in flight
    asm volatile("" ::: "memory");
    __builtin_amdgcn_s_barrier();
    __builtin_amdgcn_sched_barrier(0);

#pragma unroll 1
    for (int t = 0; t < nT; t += 2) {
        TILE_STEP(0, 1, t);
        TILE_STEP(1, 0, t + 1);
    }

    // ---- epilogue: C/D layout col=lrow, row=quad*4+v [m89-verified]
#pragma unroll
    for (int i = 0; i < 8; ++i) {
        const int row = m0 + (i >> 2) * 128 + wr * 64 + (i & 3) * 16 + quad * 4;
#pragma unroll
        for (int j = 0; j < 4; ++j) {
            const int col = n0 + (j >> 1) * 128 + wc * 32 + (j & 1) * 16 + lrow;
            const float badd = bias[col];
#pragma unroll
            for (int v = 0; v < 4; ++v)
                Out[(size_t)(row + v) * N + col] = acc[i][j][v] + badd;
        }
    }

#undef GLDS
#undef LOAD_AF
#undef LOAD_BF
#undef MFMA1
#undef MFMA_QUAD
#undef BAR_MID
#undef BAR_END
#undef VGUARD
#undef TILE_STEP
}

// ---------------------------------------------------------------------------
// tier-2 main GEMM (ws too small for xb): A fp32 converted in-kernel.
// ---------------------------------------------------------------------------
__global__ __launch_bounds__(256) void gemm_af32(
    const float* __restrict__ Af, const ushort* __restrict__ Bmat,
    const float* __restrict__ bias, float* __restrict__ Out,
    int M, int N, int K)
{
    constexpr int BM = 128, BN = 128, BK = 32;
    __shared__ __align__(16) ushort As[BM * BK];
    __shared__ __align__(16) ushort Bs[BN * BK];

    const int tid  = threadIdx.x;
    const int lane = tid & 63;
    const int w    = tid >> 6;
    const int wm   = (w >> 1) * 64;
    const int wn   = (w & 1) * 64;
    const int quad = lane >> 4;
    const int lrow = lane & 15;
    const int m0 = blockIdx.x * BM;
    const int n0 = blockIdx.y * BN;

    const int srow = (w * 2) * 16 + (lane >> 2);
    const int kofs = (lane & 3) * 8;
    const ushort* bgp0 = Bmat + (size_t)(n0 + srow) * K + kofs;
    const ushort* bgp1 = bgp0 + (size_t)16 * K;
    ushort* lB0 = &Bs[(w * 2) * 512];
    ushort* lB1 = &Bs[(w * 2 + 1) * 512];

    f32x4 acc[4][4] = {};
    const int nK = K / BK;
    for (int kt = 0; kt < nK; ++kt) {
        __syncthreads();
        __builtin_amdgcn_global_load_lds(GLOBAL_AS(bgp0), LDS_AS(lB0), 16, 0, 0);
        __builtin_amdgcn_global_load_lds(GLOBAL_AS(bgp1), LDS_AS(lB1), 16, 0, 0);
        bgp0 += BK; bgp1 += BK;
#pragma unroll
        for (int gg = 0; gg < 2; ++gg) {
            int g = tid + gg * 256;
            int row = g >> 2, kc = (g & 3) * 8;
            const float* src = Af + (size_t)(m0 + row) * K + (size_t)kt * BK + kc;
            float4 a = *(const float4*)src;
            float4 b = *(const float4*)(src + 4);
            u16x8 r;
            r[0] = f2b(a.x); r[1] = f2b(a.y); r[2] = f2b(a.z); r[3] = f2b(a.w);
            r[4] = f2b(b.x); r[5] = f2b(b.y); r[6] = f2b(b.z); r[7] = f2b(b.w);
            *reinterpret_cast<u16x8*>(&As[row * BK + kc]) = r;
        }
        __syncthreads();

        bf16x8 af[4], bfr[4];
#pragma unroll
        for (int i = 0; i < 4; ++i)
            af[i] = *reinterpret_cast<const bf16x8*>(&As[(wm + i * 16 + lrow) * BK + quad * 8]);
#pragma unroll
        for (int j = 0; j < 4; ++j)
            bfr[j] = *reinterpret_cast<const bf16x8*>(&Bs[(wn + j * 16 + lrow) * BK + quad * 8]);
#pragma unroll
        for (int i = 0; i < 4; ++i)
#pragma unroll
            for (int j = 0; j < 4; ++j)
                acc[i][j] = __builtin_amdgcn_mfma_f32_16x16x32_bf16(af[i], bfr[j], acc[i][j], 0, 0, 0);
    }

#pragma unroll
    for (int i = 0; i < 4; ++i) {
        const int row = m0 + wm + i * 16 + quad * 4;
#pragma unroll
        for (int j = 0; j < 4; ++j) {
            const int col = n0 + wn + j * 16 + lrow;
            float badd = bias[col];
#pragma unroll
            for (int v = 0; v < 4; ++v)
                Out[(size_t)(row + v) * N + col] = acc[i][j][v] + badd;
        }
    }
}

// ---------------------------------------------------------------------------
// emergency fallback (tiny ws): pure fp32, slow but correct
// ---------------------------------------------------------------------------
__global__ void naive_kernel(const float* __restrict__ x, const float* __restrict__ lA,
                             const float* __restrict__ lB, const float* __restrict__ W,
                             const float* __restrict__ bias, const float* __restrict__ lw,
                             float* __restrict__ out)
{
    __shared__ float xs[4096];
    __shared__ float h[128];
    const int m = blockIdx.x;
    for (int d = threadIdx.x; d < 4096; d += 256)
        xs[d] = x[(size_t)m * 4096 + d];
    __syncthreads();
    for (int k = threadIdx.x; k < 128; k += 256) {
        const float* arow = lA + (size_t)k * 4096;
        float s = 0.f;
        for (int d = 0; d < 4096; ++d) s += xs[d] * arow[d];
        h[k] = s;
    }
    __syncthreads();
    for (int o = threadIdx.x; o < 4096; o += 256) {
        const float* wrow = W + (size_t)o * 4096;
        float s = bias[o];
        for (int d = 0; d < 4096; ++d) s += xs[d] * wrow[d];
        for (int n = 0; n < 8; ++n) {
            const float* brow = lB + ((size_t)n * 4096 + o) * 16;
            float t = 0.f;
            for (int r = 0; r < 16; ++r) t += h[n * 16 + r] * brow[r];
            s += 2.0f * lw[n] * t;
        }
        out[(size_t)m * 4096 + o] = s;
    }
}

// ---------------------------------------------------------------------------
extern "C" void kernel_launch(void* const* d_in, const int* in_sizes, int n_in,
                              void* d_out, int out_size, void* d_ws, size_t ws_size,
                              hipStream_t stream)
{
    const float* x    = (const float*)d_in[0];  // [4,2048,4096]
    const float* lA   = (const float*)d_in[1];  // [8,16,4096]
    const float* lB   = (const float*)d_in[2];  // [8,4096,16]
    const float* W    = (const float*)d_in[3];  // [4096,4096]
    const float* bias = (const float*)d_in[4];  // [4096]
    const float* lw   = (const float*)d_in[5];  // [8]
    float* out = (float*)d_out;                 // [8192,4096] fp32

    // ws layout (bf16): [Bcat 1MiB][AcatT 1MiB][Weff 32MiB][xb 64MiB]
    ushort* Bcat  = (ushort*)d_ws;
    ushort* AcatT = Bcat + (size_t)4096 * 128;
    ushort* Weff  = AcatT + (size_t)4096 * 128;
    ushort* xb    = Weff + (size_t)4096 * 4096;
    const size_t need_t2 = (2 * (size_t)4096 * 128 + (size_t)4096 * 4096) * 2;
    const size_t need_t1 = need_t2 + (size_t)8192 * 4096 * 2;

    if (ws_size >= need_t2) {
        prep_a_kernel<<<64, 256, 0, stream>>>(lA, AcatT);
        prep_b_kernel<<<2048, 256, 0, stream>>>(lB, lw, Bcat);
        // Weff[o][d] = W[o][d] + Bcat[o][:]·AcatT[d][:]   (bf16 out, K=128)
        gemm_bt<false, false, true><<<dim3(32, 32), 256, 0, stream>>>(
            Bcat, AcatT, W, Weff, 4096, 4096, 128);
        if (ws_size >= need_t1) {
            cvtx_kernel<<<16384, 256, 0, stream>>>(x, xb);
            // out[m][o] = xb[m][:]·Weff[o][:] + bias[o]   (fp32 out)
            // 256^2 8-phase kernel: grid = (8192/256)*(4096/256) = 512
            gemm256_bias<<<dim3(512), 512, 0, stream>>>(
                xb, Weff, bias, out, 8192, 4096, 4096);
        } else {
            gemm_af32<<<dim3(64, 32), 256, 0, stream>>>(
                x, Weff, bias, out, 8192, 4096, 4096);
        }
    } else {
        naive_kernel<<<8192, 256, 0, stream>>>(x, lA, lB, W, bias, lw, out);
    }
}